// Round 10
// baseline (48.605 us; speedup 1.0000x reference)
//
#include <hip/hip_runtime.h>

// Locally-connected 2d: x[32,16,66,66], w[1,32,16,64,64,9], bias[1,32,64,64]
// out[32,32,64,64] fp32.
//
// R10: R9 fused structure with rebuilt weight staging.
//  - Per (h,w): out[b,o] = GEMM 32x32x144, kflat = kappa*16+c -> 9 MFMAs, no pad.
//  - Staging: thread owns segs {2tid, 2tid+1} (seg = o*16+c). Reads: 2x9 static
//    float4 (288 B contiguous per thread, each weight float read once grid-wide).
//    Writes: pack bf16(seg0)|bf16(seg1)<<16 -> ONE ds_write_b32 at dword
//    tid + f*256 (f = w2f*9+k static) -> 36 imm-offset writes, 2-way bank (free).
//  - No XOR swizzle: packed-layout B reads are lane-contiguous 16 B
//    (byte = 1024*(w2*9+kk) + 32*ln + 16*half) = dense conflict-free b128.
//  - x: prep_x packs xP[hh][ww][b][c] bf16 (4.5 MB, d_ws); A-frag = dwordx4.
//  - Epilogue: LDS transpose (reuse pw) + float4 stores.

#define CI_ 16
#define H_  64
#define W_  64
#define XW_ 66

typedef float f32x16 __attribute__((ext_vector_type(16)));
typedef short s16x8  __attribute__((ext_vector_type(8)));

__device__ inline unsigned f2bf_u(float f) {  // RNE float->bf16, low 16 bits
  unsigned u = __builtin_bit_cast(unsigned, f);
  u += 0x7fffu + ((u >> 16) & 1u);
  return u >> 16;
}
__device__ inline short f2bf(float f) { return (short)f2bf_u(f); }

// ---- prep_x: x[b][c][hh][ww] f32 -> xP[hh][ww][b][c] bf16 (verified R8/R9) --
__global__ __launch_bounds__(256) void prep_x(const float* __restrict__ x,
                                              short* __restrict__ xP) {
  const int t = blockIdx.x * 256 + threadIdx.x;  // 66*66*32*2 = 278784 exact
  const int oct = t & 1;
  const int b   = (t >> 1) & 31;
  const int hhww = t >> 6;
  const float* sp = x + ((size_t)b * CI_ + oct * 8) * 4356 + hhww;
  s16x8 v;
#pragma unroll
  for (int e = 0; e < 8; ++e) v[e] = f2bf(sp[(size_t)e * 4356]);
  *(s16x8*)(xP + (size_t)t * 8) = v;
}

// ---- fused main: stage weights -> LDS packed; 9 MFMAs; transpose epilogue ---
__global__ __launch_bounds__(256, 4) void lc2d_fused(
    const short* __restrict__ xP, const float* __restrict__ wt,
    const float* __restrict__ bias, float* __restrict__ out) {
  __shared__ short pw[4 * 9 * 32 * 16];  // [w2][kappa][o][c] = 36 KB (also tr)

  const int d = blockIdx.x;                      // 1024 blocks, XCD-bijective
  const int L = (d & 7) * 128 + (d >> 3);
  const int wq = L & 15;
  const int h  = L >> 4;
  const int tx = threadIdx.x;                    // 0..63
  const int w2 = threadIdx.y;                    // 0..3 (wave id = w in quad)
  const int tid = w2 * 64 + tx;                  // 0..255

  // ---- stage: segs 2tid, 2tid+1; 18 static float4 loads; 36 packed b32 writes
  {
    const float4* s0 = (const float4*)wt +
        ((size_t)(2 * tid) * H_ + h) * 144 + wq * 9;
    const float4* s1 = s0 + (size_t)H_ * 144;    // seg+1
    float4 r0[9], r1[9];
#pragma unroll
    for (int q = 0; q < 9; ++q) r0[q] = s0[q];
#pragma unroll
    for (int q = 0; q < 9; ++q) r1[q] = s1[q];

    unsigned* up = (unsigned*)pw + tid;          // dword idx tid + f*256
#pragma unroll
    for (int q = 0; q < 9; ++q) {
      const float* a = (const float*)&r0[q];
      const float* b = (const float*)&r1[q];
#pragma unroll
      for (int e = 0; e < 4; ++e) {
        const int f = 4 * q + e;                 // w2f*9 + k, 0..35
        up[f * 256] = f2bf_u(a[e]) | (f2bf_u(b[e]) << 16);
      }
    }
  }
  __syncthreads();

  const int ln   = tx & 31;                      // A-row (b) / B-col (o)
  const int half = tx >> 5;                      // c-half: c = half*8 + e
  const int w = wq * 4 + w2;

  f32x16 acc = {0,0,0,0,0,0,0,0,0,0,0,0,0,0,0,0};
  const short* ap0 = xP + ln * 16 + half * 8;
  const short* bp  = pw + (w2 * 9) * 512 + ln * 16 + half * 8;
#pragma unroll
  for (int kk = 0; kk < 9; ++kk) {
    const int i = kk / 3, j = kk - 3 * i;
    const s16x8 af = *(const s16x8*)(ap0 + (size_t)((h + i) * XW_ + (w + j)) * 512);
    const s16x8 bf = *(const s16x8*)(bp + kk * 512);
    acc = __builtin_amdgcn_mfma_f32_32x32x16_bf16(af, bf, acc, 0, 0, 0);
  }

  // ---- epilogue: C/D col(o)=ln, row(b)=(r&3)+8*(r>>2)+4*half (verified) ----
  __syncthreads();                               // pw reads done
  float* tr = (float*)pw;                        // 16 KB reuse
#pragma unroll
  for (int r = 0; r < 16; ++r) {
    const int b = (r & 3) + 8 * (r >> 2) + 4 * half;
    tr[(w2 * 32 + b) * 32 + ln] = acc[r];
  }
  __syncthreads();

  const int o = tid & 31;
  const int brow = tid >> 5;                     // 0..7
  const float4 bv = *(const float4*)(bias + ((size_t)o * H_ + h) * W_ + wq * 4);
#pragma unroll
  for (int it = 0; it < 4; ++it) {
    const int b = it * 8 + brow;
    float4 v;
    v.x = tr[(0 * 32 + b) * 32 + o] + bv.x;
    v.y = tr[(1 * 32 + b) * 32 + o] + bv.y;
    v.z = tr[(2 * 32 + b) * 32 + o] + bv.z;
    v.w = tr[(3 * 32 + b) * 32 + o] + bv.w;
    *(float4*)(out + ((size_t)b * 32 + o) * (H_ * W_) + h * W_ + wq * 4) = v;
  }
}

// ---- fallback (R7-verified, no workspace): gather MFMA ----------------------
__global__ __launch_bounds__(256, 4) void lc2d_mfma0(
    const float* __restrict__ xs, const float* __restrict__ wt,
    const float* __restrict__ bias, float* __restrict__ out) {
  __shared__ float wlds[8 * 32 * 36];
  const int d = blockIdx.x;
  const int L = (d & 7) * 128 + (d >> 3);
  const int wq = L & 15;
  const int h  = L >> 4;
  const int tx = threadIdx.x;
  const int w2 = threadIdx.y;
  const int ln = tx & 31;
  const int half = tx >> 5;
  const int tid = w2 * 64 + tx;
  const int w = wq * 4 + w2;
  f32x16 acc = {0,0,0,0,0,0,0,0,0,0,0,0,0,0,0,0};
  const int bbase = ln * 36 + w2 * 9;
  size_t abase = (size_t)ln * 69696 + (size_t)h * XW_ + w;

  for (int s = 0; s < 2; ++s) {
    const int c0 = s * 8;
    __syncthreads();
#pragma unroll
    for (int i = 0; i < 9; ++i) {
      const int f4 = tid + i * 256;
      const int cc = f4 / 288;
      const int rem = f4 - cc * 288;
      const int oo = rem / 9;
      const int q = rem - oo * 9;
      const float4* src = (const float4*)wt +
          (((size_t)oo * CI_ + (c0 + cc)) * H_ + h) * 144 + (size_t)wq * 9 + q;
      ((float4*)wlds)[f4] = *src;
    }
    __syncthreads();
#pragma unroll
    for (int cc = 0; cc < 8; ++cc) {
      const int c = c0 + cc;
      const float* ap = xs + abase + (size_t)c * 4356;
      float av[8] = {0,0,0,0,0,0,0,0};
      float bvv[8] = {0,0,0,0,0,0,0,0};
      av[0] = ap[half ? (2 * XW_ + 2) : 0];
      bvv[0] = wlds[cc * 1152 + bbase + (half ? 8 : 0)];
      if (half == 0) {
#pragma unroll
        for (int e = 1; e < 8; ++e) {
          const int i = e / 3, j = e - 3 * i;
          av[e] = ap[i * XW_ + j];
          bvv[e] = wlds[cc * 1152 + bbase + e];
        }
      }
      s16x8 af, bf;
#pragma unroll
      for (int e = 0; e < 8; ++e) { af[e] = f2bf(av[e]); bf[e] = f2bf(bvv[e]); }
      acc = __builtin_amdgcn_mfma_f32_32x32x16_bf16(af, bf, acc, 0, 0, 0);
    }
  }
  const float bvv = bias[((size_t)ln * H_ + h) * W_ + w];
#pragma unroll
  for (int r = 0; r < 16; ++r) {
    const int b = (r & 3) + 8 * (r >> 2) + 4 * half;
    out[(((size_t)b * 32 + ln) * H_ + h) * W_ + w] = acc[r] + bvv;
  }
}

extern "C" void kernel_launch(void* const* d_in, const int* in_sizes, int n_in,
                              void* d_out, int out_size, void* d_ws, size_t ws_size,
                              hipStream_t stream) {
  const float* x    = (const float*)d_in[0];
  const float* wt   = (const float*)d_in[1];
  const float* bias = (const float*)d_in[2];
  float* out = (float*)d_out;

  const size_t xp_bytes = (size_t)66 * 66 * 32 * 16 * sizeof(short);  // 4.46 MB
  dim3 block(64, 4, 1);
  if (ws_size >= xp_bytes) {
    short* xP = (short*)d_ws;
    prep_x<<<1089, 256, 0, stream>>>(x, xP);
    lc2d_fused<<<1024, block, 0, stream>>>(xP, wt, bias, out);
  } else {
    lc2d_mfma0<<<1024, block, 0, stream>>>(x, wt, bias, out);
  }
}

// Round 12
// 45.623 us; speedup vs baseline: 1.0654x; 1.0654x over previous
//
#include <hip/hip_runtime.h>

// Locally-connected 2d: x[32,16,66,66], w[1,32,16,64,64,9], bias[1,32,64,64]
// out[32,32,64,64] fp32.
//
// R12 = R11 resubmitted verbatim after infra failure (never measured).
// R11 = R9's proven staging (dense f4 reads tid+256i, swizzled b16 scatter)
//       + af (x-fragment) register prefetch issued BEFORE the staging barrier
//       + incremental seg/q arithmetic (no per-load divides).
// R10 lesson: per-thread-chunk reads (stride 288B) = 64 lines/instr -> 4x L2
// request amplification -> regression. Dense reads = 16 lines/KB. R9 swizzle
// (granule ^= (o^k)&7, both sides) is numerically verified (absmax 0.03125).
//
// Per (h,w): out[b,o] = GEMM 32x32x144, kflat=kappa*16+c -> 9 MFMAs, no pad.

#define CI_ 16
#define H_  64
#define W_  64
#define XW_ 66

typedef float f32x16 __attribute__((ext_vector_type(16)));
typedef short s16x8  __attribute__((ext_vector_type(8)));

__device__ inline short f2bf(float f) {  // RNE float->bf16
  unsigned u = __builtin_bit_cast(unsigned, f);
  u += 0x7fffu + ((u >> 16) & 1u);
  return (short)(u >> 16);
}

// ---- prep_x: x[b][c][hh][ww] f32 -> xP[hh][ww][b][c] bf16 (verified R8-R10) -
__global__ __launch_bounds__(256) void prep_x(const float* __restrict__ x,
                                              short* __restrict__ xP) {
  const int t = blockIdx.x * 256 + threadIdx.x;  // 66*66*32*2 = 278784 exact
  const int oct = t & 1;
  const int b   = (t >> 1) & 31;
  const int hhww = t >> 6;
  const float* sp = x + ((size_t)b * CI_ + oct * 8) * 4356 + hhww;
  s16x8 v;
#pragma unroll
  for (int e = 0; e < 8; ++e) v[e] = f2bf(sp[(size_t)e * 4356]);
  *(s16x8*)(xP + (size_t)t * 8) = v;
}

// ---- fused main ------------------------------------------------------------
__global__ __launch_bounds__(256, 4) void lc2d_fused(
    const short* __restrict__ xP, const float* __restrict__ wt,
    const float* __restrict__ bias, float* __restrict__ out) {
  __shared__ short pw[4 * 9 * 32 * 16];  // [w2][kappa][o][c] + swizzle, 36 KB

  const int d = blockIdx.x;                      // 1024 blocks, XCD-bijective
  const int L = (d & 7) * 128 + (d >> 3);
  const int wq = L & 15;
  const int h  = L >> 4;
  const int tx = threadIdx.x;                    // 0..63
  const int w2 = threadIdx.y;                    // 0..3 (wave id = w in quad)
  const int tid = w2 * 64 + tx;                  // 0..255
  const int ln   = tx & 31;                      // A-row (b) / B-col (o)
  const int half = tx >> 5;                      // c-half: c = half*8 + e
  const int w = wq * 4 + w2;

  // Incremental (seg, q) for dense f4 indices f4 = tid + 256*i  (256 = 9*28+4)
  int segA[18], qA[18];
  {
    int seg = (tid * 57) >> 9;                   // tid/9 (valid tid<512)
    int q   = tid - 9 * seg;
#pragma unroll
    for (int i = 0; i < 18; ++i) {
      segA[i] = seg; qA[i] = q;
      const int t2 = q + 4;
      const int ge = (t2 >= 9) ? 1 : 0;
      q = t2 - 9 * ge;
      seg += 28 + ge;
    }
  }

  // ---- issue af prefetch (x fragments; independent of LDS) -----------------
  const short* ap0 = xP + ln * 16 + half * 8;
  s16x8 af[9];
#pragma unroll
  for (int kk = 0; kk < 9; ++kk) {
    const int i = kk / 3, j = kk - 3 * i;
    af[kk] = *(const s16x8*)(ap0 + (size_t)((h + i) * XW_ + (w + j)) * 512);
  }

  // ---- issue staging loads: dense, 1KB/wave-instr, each float once ---------
  float4 vst[18];
#pragma unroll
  for (int i = 0; i < 18; ++i) {
    vst[i] = ((const float4*)wt)[((size_t)segA[i] * H_ + h) * 144 + wq * 9 + qA[i]];
  }

  // ---- pack/scatter into swizzled LDS (R9-verified mapping) ----------------
#pragma unroll
  for (int i = 0; i < 18; ++i) {
    const int sg = segA[i], qq = qA[i];
    const int o  = sg >> 4;
    const int s3 = sg >> 3, s7 = sg & 7;
    const float* vv = (const float*)&vst[i];
#pragma unroll
    for (int e = 0; e < 4; ++e) {
      const int flat = 4 * qq + e;               // w2f*9 + k, 0..35
      const int k = flat - 9 * ((flat * 57) >> 9);
      const int g = ((flat << 6) + s3) ^ ((o ^ k) & 7);
      pw[(g << 3) | s7] = f2bf(vv[e]);
    }
  }
  __syncthreads();

  // ---- 9 MFMAs: af from regs, bf from swizzled LDS (dense b128) ------------
  f32x16 acc = {0,0,0,0,0,0,0,0,0,0,0,0,0,0,0,0};
#pragma unroll
  for (int kk = 0; kk < 9; ++kk) {
    int g = ((w2 * 9 + kk) * 32 + ln) * 2 + half;
    g ^= (ln ^ kk) & 7;
    const s16x8 bf = *(const s16x8*)(pw + (g << 3));
    acc = __builtin_amdgcn_mfma_f32_32x32x16_bf16(af[kk], bf, acc, 0, 0, 0);
  }

  // ---- epilogue: C/D col(o)=ln, row(b)=(r&3)+8*(r>>2)+4*half (verified) ----
  __syncthreads();                               // pw reads done
  float* tr = (float*)pw;                        // 16 KB reuse
#pragma unroll
  for (int r = 0; r < 16; ++r) {
    const int b = (r & 3) + 8 * (r >> 2) + 4 * half;
    tr[(w2 * 32 + b) * 32 + ln] = acc[r];
  }
  __syncthreads();

  const int o = tid & 31;
  const int brow = tid >> 5;                     // 0..7
  const float4 bv = *(const float4*)(bias + ((size_t)o * H_ + h) * W_ + wq * 4);
#pragma unroll
  for (int it = 0; it < 4; ++it) {
    const int b = it * 8 + brow;
    float4 v;
    v.x = tr[(0 * 32 + b) * 32 + o] + bv.x;
    v.y = tr[(1 * 32 + b) * 32 + o] + bv.y;
    v.z = tr[(2 * 32 + b) * 32 + o] + bv.z;
    v.w = tr[(3 * 32 + b) * 32 + o] + bv.w;
    *(float4*)(out + ((size_t)b * 32 + o) * (H_ * W_) + h * W_ + wq * 4) = v;
  }
}

// ---- fallback (R7-verified, no workspace): gather MFMA ----------------------
__global__ __launch_bounds__(256, 4) void lc2d_mfma0(
    const float* __restrict__ xs, const float* __restrict__ wt,
    const float* __restrict__ bias, float* __restrict__ out) {
  __shared__ float wlds[8 * 32 * 36];
  const int d = blockIdx.x;
  const int L = (d & 7) * 128 + (d >> 3);
  const int wq = L & 15;
  const int h  = L >> 4;
  const int tx = threadIdx.x;
  const int w2 = threadIdx.y;
  const int ln = tx & 31;
  const int half = tx >> 5;
  const int tid = w2 * 64 + tx;
  const int w = wq * 4 + w2;
  f32x16 acc = {0,0,0,0,0,0,0,0,0,0,0,0,0,0,0,0};
  const int bbase = ln * 36 + w2 * 9;
  size_t abase = (size_t)ln * 69696 + (size_t)h * XW_ + w;

  for (int s = 0; s < 2; ++s) {
    const int c0 = s * 8;
    __syncthreads();
#pragma unroll
    for (int i = 0; i < 9; ++i) {
      const int f4 = tid + i * 256;
      const int cc = f4 / 288;
      const int rem = f4 - cc * 288;
      const int oo = rem / 9;
      const int q = rem - oo * 9;
      const float4* src = (const float4*)wt +
          (((size_t)oo * CI_ + (c0 + cc)) * H_ + h) * 144 + (size_t)wq * 9 + q;
      ((float4*)wlds)[f4] = *src;
    }
    __syncthreads();
#pragma unroll
    for (int cc = 0; cc < 8; ++cc) {
      const int c = c0 + cc;
      const float* ap = xs + abase + (size_t)c * 4356;
      float av[8] = {0,0,0,0,0,0,0,0};
      float bvv[8] = {0,0,0,0,0,0,0,0};
      av[0] = ap[half ? (2 * XW_ + 2) : 0];
      bvv[0] = wlds[cc * 1152 + bbase + (half ? 8 : 0)];
      if (half == 0) {
#pragma unroll
        for (int e = 1; e < 8; ++e) {
          const int i = e / 3, j = e - 3 * i;
          av[e] = ap[i * XW_ + j];
          bvv[e] = wlds[cc * 1152 + bbase + e];
        }
      }
      s16x8 afr, bfr;
#pragma unroll
      for (int e = 0; e < 8; ++e) { afr[e] = f2bf(av[e]); bfr[e] = f2bf(bvv[e]); }
      acc = __builtin_amdgcn_mfma_f32_32x32x16_bf16(afr, bfr, acc, 0, 0, 0);
    }
  }
  const float bvv = bias[((size_t)ln * H_ + h) * W_ + w];
#pragma unroll
  for (int r = 0; r < 16; ++r) {
    const int b = (r & 3) + 8 * (r >> 2) + 4 * half;
    out[(((size_t)b * 32 + ln) * H_ + h) * W_ + w] = acc[r] + bvv;
  }
}

extern "C" void kernel_launch(void* const* d_in, const int* in_sizes, int n_in,
                              void* d_out, int out_size, void* d_ws, size_t ws_size,
                              hipStream_t stream) {
  const float* x    = (const float*)d_in[0];
  const float* wt   = (const float*)d_in[1];
  const float* bias = (const float*)d_in[2];
  float* out = (float*)d_out;

  const size_t xp_bytes = (size_t)66 * 66 * 32 * 16 * sizeof(short);  // 4.46 MB
  dim3 block(64, 4, 1);
  if (ws_size >= xp_bytes) {
    short* xP = (short*)d_ws;
    prep_x<<<1089, 256, 0, stream>>>(x, xP);
    lc2d_fused<<<1024, block, 0, stream>>>(xP, wt, bias, out);
  } else {
    lc2d_mfma0<<<1024, block, 0, stream>>>(x, wt, bias, out);
  }
}

// Round 14
// 39.023 us; speedup vs baseline: 1.2456x; 1.1691x over previous
//
#include <hip/hip_runtime.h>

// Locally-connected 2d: x[32,16,66,66], w[1,32,16,64,64,9], bias[1,32,64,64]
// out[32,32,64,64] fp32.
//
// R14 = R13 with the division bug fixed (R13 crash: hand-rolled (f4*114)>>10
// for f4/9 is wrong at f4>=4600 -> OOB global read + LDS overflow -> abort).
// Exact compiler division by 9 everywhere (emits correct magic-mul).
//  - af (x-fragment) prefetch issued before staging barrier (hide x latency).
//  - staging split in 2 halves of 9 dense float4 (36 VGPR live, no spill;
//    R12 lesson: 18 float4 + af[9] spilled at the 64-VGPR heuristic).
//  - plain __launch_bounds__(256): no min-wave cap (R5 spill lesson).
// Per (h,w): out[b,o] = GEMM 32x32x144, kflat=kappa*16+c -> 9 MFMAs, no pad.
// Staging reads dense (f4 = tid + 256*i, 1KB/wave-instr, each float once).

#define CI_ 16
#define H_  64
#define W_  64
#define XW_ 66

typedef float f32x16 __attribute__((ext_vector_type(16)));
typedef short s16x8  __attribute__((ext_vector_type(8)));

__device__ inline short f2bf(float f) {  // RNE float->bf16
  unsigned u = __builtin_bit_cast(unsigned, f);
  u += 0x7fffu + ((u >> 16) & 1u);
  return (short)(u >> 16);
}

// ---- prep_x: x[b][c][hh][ww] f32 -> xP[hh][ww][b][c] bf16 (verified R8-R12) -
__global__ __launch_bounds__(256) void prep_x(const float* __restrict__ x,
                                              short* __restrict__ xP) {
  const int t = blockIdx.x * 256 + threadIdx.x;  // 66*66*32*2 = 278784 exact
  const int oct = t & 1;
  const int b   = (t >> 1) & 31;
  const int hhww = t >> 6;
  const float* sp = x + ((size_t)b * CI_ + oct * 8) * 4356 + hhww;
  s16x8 v;
#pragma unroll
  for (int e = 0; e < 8; ++e) v[e] = f2bf(sp[(size_t)e * 4356]);
  *(s16x8*)(xP + (size_t)t * 8) = v;
}

// ---- fused main ------------------------------------------------------------
__global__ __launch_bounds__(256) void lc2d_fused(
    const short* __restrict__ xP, const float* __restrict__ wt,
    const float* __restrict__ bias, float* __restrict__ out) {
  __shared__ short pw[4 * 9 * 32 * 16];  // [w2][kappa][o][c] + swizzle, 36 KB

  const int d = blockIdx.x;                      // 1024 blocks, XCD-bijective
  const int L = (d & 7) * 128 + (d >> 3);
  const int wq = L & 15;
  const int h  = L >> 4;
  const int tx = threadIdx.x;                    // 0..63
  const int w2 = threadIdx.y;                    // 0..3 (wave id = w in quad)
  const int tid = w2 * 64 + tx;                  // 0..255
  const int ln   = tx & 31;                      // A-row (b) / B-col (o)
  const int half = tx >> 5;                      // c-half: c = half*8 + e
  const int w = wq * 4 + w2;

  // ---- af prefetch (x fragments; consumed after the barrier) ---------------
  const short* ap0 = xP + ln * 16 + half * 8;
  s16x8 af[9];
#pragma unroll
  for (int kk = 0; kk < 9; ++kk) {
    const int i = kk / 3, j = kk - 3 * i;
    af[kk] = *(const s16x8*)(ap0 + (size_t)((h + i) * XW_ + (w + j)) * 512);
  }

  // ---- staging: 2 halves x 9 dense float4 (f4 = tid + 256*i) ---------------
#pragma unroll
  for (int hf = 0; hf < 2; ++hf) {
    float4 vst[9];
#pragma unroll
    for (int i = 0; i < 9; ++i) {
      const int f4 = tid + 256 * (hf * 9 + i);   // 0..4607
      const int seg = f4 / 9;                    // exact (compiler magic-mul)
      const int q   = f4 % 9;
      vst[i] = ((const float4*)wt)[((size_t)seg * H_ + h) * 144 + wq * 9 + q];
    }
#pragma unroll
    for (int i = 0; i < 9; ++i) {
      const int f4 = tid + 256 * (hf * 9 + i);
      const int seg = f4 / 9;
      const int q   = f4 % 9;
      const int o  = seg >> 4;
      const int s3 = seg >> 3, s7 = seg & 7;
      const float* vv = (const float*)&vst[i];
#pragma unroll
      for (int e = 0; e < 4; ++e) {
        const int flat = 4 * q + e;              // w2f*9 + k, 0..35
        const int k = flat - 9 * (flat / 9);     // exact
        const int g = ((flat << 6) + s3) ^ ((o ^ k) & 7);
        pw[(g << 3) | s7] = f2bf(vv[e]);
      }
    }
  }
  __syncthreads();

  // ---- 9 MFMAs: af from regs, bf from swizzled LDS -------------------------
  f32x16 acc = {0,0,0,0,0,0,0,0,0,0,0,0,0,0,0,0};
#pragma unroll
  for (int kk = 0; kk < 9; ++kk) {
    int g = ((w2 * 9 + kk) * 32 + ln) * 2 + half;
    g ^= (ln ^ kk) & 7;
    const s16x8 bf = *(const s16x8*)(pw + (g << 3));
    acc = __builtin_amdgcn_mfma_f32_32x32x16_bf16(af[kk], bf, acc, 0, 0, 0);
  }

  // ---- epilogue: C/D col(o)=ln, row(b)=(r&3)+8*(r>>2)+4*half (verified) ----
  __syncthreads();                               // pw reads done
  float* tr = (float*)pw;                        // 16 KB reuse
#pragma unroll
  for (int r = 0; r < 16; ++r) {
    const int b = (r & 3) + 8 * (r >> 2) + 4 * half;
    tr[(w2 * 32 + b) * 32 + ln] = acc[r];
  }
  __syncthreads();

  const int o = tid & 31;
  const int brow = tid >> 5;                     // 0..7
  const float4 bv = *(const float4*)(bias + ((size_t)o * H_ + h) * W_ + wq * 4);
#pragma unroll
  for (int it = 0; it < 4; ++it) {
    const int b = it * 8 + brow;
    float4 v;
    v.x = tr[(0 * 32 + b) * 32 + o] + bv.x;
    v.y = tr[(1 * 32 + b) * 32 + o] + bv.y;
    v.z = tr[(2 * 32 + b) * 32 + o] + bv.z;
    v.w = tr[(3 * 32 + b) * 32 + o] + bv.w;
    *(float4*)(out + ((size_t)b * 32 + o) * (H_ * W_) + h * W_ + wq * 4) = v;
  }
}

// ---- fallback (R7-verified, no workspace): gather MFMA ----------------------
__global__ __launch_bounds__(256, 4) void lc2d_mfma0(
    const float* __restrict__ xs, const float* __restrict__ wt,
    const float* __restrict__ bias, float* __restrict__ out) {
  __shared__ float wlds[8 * 32 * 36];
  const int d = blockIdx.x;
  const int L = (d & 7) * 128 + (d >> 3);
  const int wq = L & 15;
  const int h  = L >> 4;
  const int tx = threadIdx.x;
  const int w2 = threadIdx.y;
  const int ln = tx & 31;
  const int half = tx >> 5;
  const int tid = w2 * 64 + tx;
  const int w = wq * 4 + w2;
  f32x16 acc = {0,0,0,0,0,0,0,0,0,0,0,0,0,0,0,0};
  const int bbase = ln * 36 + w2 * 9;
  size_t abase = (size_t)ln * 69696 + (size_t)h * XW_ + w;

  for (int s = 0; s < 2; ++s) {
    const int c0 = s * 8;
    __syncthreads();
#pragma unroll
    for (int i = 0; i < 9; ++i) {
      const int f4 = tid + i * 256;
      const int cc = f4 / 288;
      const int rem = f4 - cc * 288;
      const int oo = rem / 9;
      const int q = rem - oo * 9;
      const float4* src = (const float4*)wt +
          (((size_t)oo * CI_ + (c0 + cc)) * H_ + h) * 144 + (size_t)wq * 9 + q;
      ((float4*)wlds)[f4] = *src;
    }
    __syncthreads();
#pragma unroll
    for (int cc = 0; cc < 8; ++cc) {
      const int c = c0 + cc;
      const float* ap = xs + abase + (size_t)c * 4356;
      float av[8] = {0,0,0,0,0,0,0,0};
      float bvv[8] = {0,0,0,0,0,0,0,0};
      av[0] = ap[half ? (2 * XW_ + 2) : 0];
      bvv[0] = wlds[cc * 1152 + bbase + (half ? 8 : 0)];
      if (half == 0) {
#pragma unroll
        for (int e = 1; e < 8; ++e) {
          const int i = e / 3, j = e - 3 * i;
          av[e] = ap[i * XW_ + j];
          bvv[e] = wlds[cc * 1152 + bbase + e];
        }
      }
      s16x8 afr, bfr;
#pragma unroll
      for (int e = 0; e < 8; ++e) { afr[e] = f2bf(av[e]); bfr[e] = f2bf(bvv[e]); }
      acc = __builtin_amdgcn_mfma_f32_32x32x16_bf16(afr, bfr, acc, 0, 0, 0);
    }
  }
  const float bvv = bias[((size_t)ln * H_ + h) * W_ + w];
#pragma unroll
  for (int r = 0; r < 16; ++r) {
    const int b = (r & 3) + 8 * (r >> 2) + 4 * half;
    out[(((size_t)b * 32 + ln) * H_ + h) * W_ + w] = acc[r] + bvv;
  }
}

extern "C" void kernel_launch(void* const* d_in, const int* in_sizes, int n_in,
                              void* d_out, int out_size, void* d_ws, size_t ws_size,
                              hipStream_t stream) {
  const float* x    = (const float*)d_in[0];
  const float* wt   = (const float*)d_in[1];
  const float* bias = (const float*)d_in[2];
  float* out = (float*)d_out;

  const size_t xp_bytes = (size_t)66 * 66 * 32 * 16 * sizeof(short);  // 4.46 MB
  dim3 block(64, 4, 1);
  if (ws_size >= xp_bytes) {
    short* xP = (short*)d_ws;
    prep_x<<<1089, 256, 0, stream>>>(x, xP);
    lc2d_fused<<<1024, block, 0, stream>>>(xP, wt, bias, out);
  } else {
    lc2d_mfma0<<<1024, block, 0, stream>>>(x, wt, bias, out);
  }
}